// Round 1
// baseline (431.246 us; speedup 1.0000x reference)
//
#include <hip/hip_runtime.h>
#include <hip/hip_bf16.h>
#include <stdint.h>

#define T_TOK 4096
#define T1N   4097
#define DMODEL 512

typedef __attribute__((ext_vector_type(8))) short bf16x8;
typedef __attribute__((ext_vector_type(4))) float f32x4;

// ---------------- weight transpose + bf16 cast: out[m][n][k] = W[m.layer][k][n] ----------------
__global__ __launch_bounds__(256) void wt_kernel(
    const float* __restrict__ Wq, const float* __restrict__ Wk,
    const float* __restrict__ Wv, const float* __restrict__ Wo,
    const float* __restrict__ W1, const float* __restrict__ W2,
    __hip_bfloat16* __restrict__ out) {
  int m = blockIdx.z;          // 0..11 : kind*2 + layer
  int kind = m >> 1, layer = m & 1;
  const float* src = kind==0?Wq: kind==1?Wk: kind==2?Wv: kind==3?Wo: kind==4?W1:W2;
  src += (size_t)layer*DMODEL*DMODEL;
  __hip_bfloat16* dst = out + (size_t)m*DMODEL*DMODEL;
  __shared__ float tile[32][33];
  int bn = blockIdx.x*32;   // n block
  int bk = blockIdx.y*32;   // k block
  int tx = threadIdx.x & 31, ty = threadIdx.x >> 5;
  for (int r = ty; r < 32; r += 8)
    tile[r][tx] = src[(size_t)(bk + r)*DMODEL + bn + tx];   // tile[kk][nn]
  __syncthreads();
  for (int r = ty; r < 32; r += 8)
    dst[(size_t)(bn + r)*DMODEL + bk + tx] = __float2bfloat16(tile[tx][r]); // dst[n][k]=src[k][n]
}

// ---------------- embedding + sinusoidal PE + seg_start ----------------
__global__ __launch_bounds__(256) void embed_kernel(
    const int* __restrict__ aseq, const int* __restrict__ bid,
    const float* __restrict__ Wt, const float* __restrict__ bt,
    const float* __restrict__ Wa, const float* __restrict__ ba,
    const float* __restrict__ sosv,
    float* __restrict__ x, __hip_bfloat16* __restrict__ xb,
    int* __restrict__ ss) {
  int i = blockIdx.x;
  int tid = threadIdx.x;
  int d0 = tid * 2;
  float o0, o1;
  if (i == 0) {
    o0 = sosv[d0]; o1 = sosv[d0+1];
  } else {
    int t = i - 1;
    int a0 = aseq[2*t], a1 = aseq[2*t+1];
    int key = bid[t];
    int lo = 0, hi = t;
    while (lo < hi) { int mid = (lo+hi) >> 1; if (bid[mid] < key) lo = mid + 1; else hi = mid; }
    if (tid == 0) ss[t] = lo;
    float pos = (float)(t - lo);
    float dv = __expf(-9.210340371976184f * (float)d0 * (1.0f/(float)DMODEL));
    float ang = pos * dv;
    float sn = sinf(ang), cs = cosf(ang);
    o0 = Wt[(size_t)a0*DMODEL + d0]   + bt[d0]   + Wa[(size_t)(a1+1)*DMODEL + d0]   + ba[d0]   + sn;
    o1 = Wt[(size_t)a0*DMODEL + d0+1] + bt[d0+1] + Wa[(size_t)(a1+1)*DMODEL + d0+1] + ba[d0+1] + cs;
  }
  size_t base = (size_t)i*DMODEL + d0;
  x[base] = o0; x[base+1] = o1;
  xb[base] = __float2bfloat16(o0); xb[base+1] = __float2bfloat16(o1);
}

// ---------------- bf16 MFMA GEMM: C[M,512] = A[M,512] @ B + bias ; B given as Bt[n][k] ----------------
template<int ACT, bool WF32, bool WB16>
__device__ __forceinline__ void gemm_body(
    const __hip_bfloat16* __restrict__ A, const __hip_bfloat16* __restrict__ Bt,
    const float* __restrict__ bias, float* __restrict__ Cf,
    __hip_bfloat16* __restrict__ Cb, int M) {
  constexpr int K = 512, N = 512;
  __shared__ __align__(16) __hip_bfloat16 As[64][72];
  __shared__ __align__(16) __hip_bfloat16 Bs[64][72];
  const int tid = threadIdx.x;
  const int m0 = blockIdx.x * 64;
  const int n0 = blockIdx.y * 64;
  const int lane = tid & 63, wave = tid >> 6;
  const int wm = wave >> 1, wn = wave & 1;
  f32x4 acc[2][2] = {};
  const int r0 = tid >> 3;          // 0..31
  const int koff = (tid & 7) * 8;   // 0..56
  const uint4 zero4 = {0,0,0,0};
  for (int k0 = 0; k0 < K; k0 += 64) {
    __syncthreads();
    #pragma unroll
    for (int rr = 0; rr < 2; rr++) {
      int row = r0 + rr*32;
      int grow = m0 + row;
      uint4 av = (grow < M) ? *(const uint4*)(A + (size_t)grow*K + k0 + koff) : zero4;
      *(uint4*)&As[row][koff] = av;
      uint4 bv = *(const uint4*)(Bt + (size_t)(n0+row)*K + k0 + koff);
      *(uint4*)&Bs[row][koff] = bv;
    }
    __syncthreads();
    #pragma unroll
    for (int kc = 0; kc < 64; kc += 32) {
      bf16x8 af[2], bf[2];
      #pragma unroll
      for (int i2 = 0; i2 < 2; i2++) {
        af[i2] = *(const bf16x8*)&As[wm*32 + i2*16 + (lane&15)][kc + (lane>>4)*8];
        bf[i2] = *(const bf16x8*)&Bs[wn*32 + i2*16 + (lane&15)][kc + (lane>>4)*8];
      }
      #pragma unroll
      for (int mi = 0; mi < 2; mi++)
        #pragma unroll
        for (int ni = 0; ni < 2; ni++)
          acc[mi][ni] = __builtin_amdgcn_mfma_f32_16x16x32_bf16(af[mi], bf[ni], acc[mi][ni], 0, 0, 0);
    }
  }
  #pragma unroll
  for (int mi = 0; mi < 2; mi++) {
    int rbase = m0 + wm*32 + mi*16 + ((lane>>4)<<2);
    #pragma unroll
    for (int ni = 0; ni < 2; ni++) {
      int col = n0 + wn*32 + ni*16 + (lane&15);
      float bb = bias[col];
      #pragma unroll
      for (int r = 0; r < 4; r++) {
        int row = rbase + r;
        if (row < M) {
          float val = acc[mi][ni][r] + bb;
          if (ACT == 1) val = fmaxf(val, 0.0f);
          if (WF32) Cf[(size_t)row*N + col] = val;
          if (WB16) Cb[(size_t)row*N + col] = __float2bfloat16(val);
        }
      }
    }
  }
}

template<int ACT, bool WF32, bool WB16>
__global__ __launch_bounds__(256) void gemm_one(
    const __hip_bfloat16* __restrict__ A, const __hip_bfloat16* __restrict__ Bt,
    const float* __restrict__ bias, float* __restrict__ Cf,
    __hip_bfloat16* __restrict__ Cb, int M) {
  gemm_body<ACT,WF32,WB16>(A, Bt, bias, Cf, Cb, M);
}

__global__ __launch_bounds__(256) void gemm_qkv(
    const __hip_bfloat16* __restrict__ A,
    const __hip_bfloat16* __restrict__ B0, const __hip_bfloat16* __restrict__ B1,
    const __hip_bfloat16* __restrict__ B2,
    const float* __restrict__ bias0, const float* __restrict__ bias1, const float* __restrict__ bias2,
    float* __restrict__ C0, float* __restrict__ C1, float* __restrict__ C2, int M) {
  int z = blockIdx.z;
  const __hip_bfloat16* Bt = (z==0) ? B0 : (z==1) ? B1 : B2;
  const float* bias = (z==0) ? bias0 : (z==1) ? bias1 : bias2;
  float* Cf = (z==0) ? C0 : (z==1) ? C1 : C2;
  gemm_body<0,true,false>(A, Bt, bias, Cf, nullptr, M);
}

// ---------------- block-sparse causal attention (f32, flash-style, SOS column) ----------------
__global__ __launch_bounds__(256) void attn_kernel(
    const float* __restrict__ q, const float* __restrict__ k,
    const float* __restrict__ v, const int* __restrict__ ss,
    __hip_bfloat16* __restrict__ out) {
  const int h  = blockIdx.y;
  const int i0 = blockIdx.x * 64;
  const int tid = threadIdx.x;
  const int qi = tid >> 2;     // query within tile 0..63
  const int c  = tid & 3;      // dim-group
  const int irow = i0 + qi;
  const bool valid = irow < T1N;
  const int dbase = h*64 + c*16;
  __shared__ __align__(16) float Ks[64][68];
  __shared__ __align__(16) float Vs[64][68];

  float qreg[16];
  if (valid) {
    const float* qp = q + (size_t)irow*DMODEL + dbase;
    #pragma unroll
    for (int e = 0; e < 16; e++) qreg[e] = qp[e];
  } else {
    #pragma unroll
    for (int e = 0; e < 16; e++) qreg[e] = 0.0f;
  }
  int jlo = 0x7fffffff;
  if (valid && irow >= 1) jlo = ss[irow-1] + 1;

  // SOS key (row 0) is always allowed: initialize online softmax with it.
  float part = 0.0f;
  {
    const float* kp = k + dbase;
    #pragma unroll
    for (int e = 0; e < 16; e++) part += qreg[e]*kp[e];
  }
  part += __shfl_xor(part, 1);
  part += __shfl_xor(part, 2);
  float m = part * 0.125f;
  float lsum = 1.0f;
  float o[16];
  {
    const float* vp = v + dbase;
    #pragma unroll
    for (int e = 0; e < 16; e++) o[e] = vp[e];
  }

  const int minss = ss[(i0 > 0) ? (i0 - 1) : 0];  // seg_start monotone => min over tile
  const int kb_lo = ((minss + 1) >> 6) << 6;
  const int jmax = (i0 + 63 < T1N - 1) ? (i0 + 63) : (T1N - 1);

  for (int kb = kb_lo; kb <= jmax; kb += 64) {
    __syncthreads();
    for (int idx = tid; idx < 64*16; idx += 256) {
      int r = idx >> 4, c4 = idx & 15;
      int grow = kb + r;
      float4 kv4, vv4;
      if (grow < T1N) {
        kv4 = *(const float4*)(k + (size_t)grow*DMODEL + h*64 + c4*4);
        vv4 = *(const float4*)(v + (size_t)grow*DMODEL + h*64 + c4*4);
      } else {
        kv4 = make_float4(0.f,0.f,0.f,0.f); vv4 = make_float4(0.f,0.f,0.f,0.f);
      }
      *(float4*)&Ks[r][c4*4] = kv4;
      *(float4*)&Vs[r][c4*4] = vv4;
    }
    __syncthreads();
    for (int j = 0; j < 64; j++) {
      int jrow = kb + j;
      float p2 = 0.0f;
      #pragma unroll
      for (int e = 0; e < 16; e++) p2 += qreg[e]*Ks[j][c*16+e];
      p2 += __shfl_xor(p2, 1);
      p2 += __shfl_xor(p2, 2);
      float s = (jrow >= jlo && jrow <= irow) ? p2*0.125f : -1e30f;
      float mnew = fmaxf(m, s);
      float corr = __expf(m - mnew);
      float p = __expf(s - mnew);
      lsum = lsum*corr + p;
      #pragma unroll
      for (int e = 0; e < 16; e++) o[e] = o[e]*corr + p*Vs[j][c*16+e];
      m = mnew;
    }
  }
  if (valid) {
    float inv = 1.0f / lsum;
    __hip_bfloat16* op = out + (size_t)irow*DMODEL + dbase;
    #pragma unroll
    for (int e = 0; e < 16; e++) op[e] = __float2bfloat16(o[e]*inv);
  }
}

// ---------------- residual + LayerNorm ----------------
__global__ __launch_bounds__(256) void ln_kernel(
    const float* __restrict__ xin, const float* __restrict__ yin,
    const float* __restrict__ g, const float* __restrict__ b,
    float* __restrict__ xout, __hip_bfloat16* __restrict__ xbout) {
  int row = blockIdx.x;
  int tid = threadIdx.x;
  const float* xp = xin + (size_t)row*DMODEL;
  const float* yp = yin + (size_t)row*DMODEL;
  float v0 = xp[tid] + yp[tid];
  float v1 = xp[tid+256] + yp[tid+256];
  float s = v0 + v1, sq = v0*v0 + v1*v1;
  #pragma unroll
  for (int off = 1; off < 64; off <<= 1) {
    s  += __shfl_xor(s, off);
    sq += __shfl_xor(sq, off);
  }
  __shared__ float ls[4], lq[4];
  int wave = tid >> 6;
  if ((tid & 63) == 0) { ls[wave] = s; lq[wave] = sq; }
  __syncthreads();
  s  = ls[0] + ls[1] + ls[2] + ls[3];
  sq = lq[0] + lq[1] + lq[2] + lq[3];
  float mean = s * (1.0f/512.0f);
  float var  = sq * (1.0f/512.0f) - mean*mean;
  float rstd = rsqrtf(var + 1e-5f);
  float o0 = (v0 - mean)*rstd*g[tid]     + b[tid];
  float o1 = (v1 - mean)*rstd*g[tid+256] + b[tid+256];
  size_t base = (size_t)row*DMODEL;
  xout[base + tid]       = o0;
  xout[base + tid + 256] = o1;
  xbout[base + tid]       = __float2bfloat16(o0);
  xbout[base + tid + 256] = __float2bfloat16(o1);
}

extern "C" void kernel_launch(void* const* d_in, const int* in_sizes, int n_in,
                              void* d_out, int out_size, void* d_ws, size_t ws_size,
                              hipStream_t stream) {
  const int*   aseq   = (const int*)d_in[0];
  const int*   bid    = (const int*)d_in[1];
  const float* W_type = (const float*)d_in[2];
  const float* b_type = (const float*)d_in[3];
  const float* W_arg  = (const float*)d_in[4];
  const float* b_arg  = (const float*)d_in[5];
  const float* sosv   = (const float*)d_in[6];
  const float* Wq = (const float*)d_in[7];
  const float* bq = (const float*)d_in[8];
  const float* Wk = (const float*)d_in[9];
  const float* bk = (const float*)d_in[10];
  const float* Wv = (const float*)d_in[11];
  const float* bv = (const float*)d_in[12];
  const float* Wo = (const float*)d_in[13];
  const float* bo = (const float*)d_in[14];
  const float* ln1g = (const float*)d_in[15];
  const float* ln1b = (const float*)d_in[16];
  const float* W1 = (const float*)d_in[17];
  const float* b1 = (const float*)d_in[18];
  const float* W2 = (const float*)d_in[19];
  const float* b2 = (const float*)d_in[20];
  const float* ln2g = (const float*)d_in[21];
  const float* ln2b = (const float*)d_in[22];

  char* wsp = (char*)d_ws;
  size_t off = 0;
  auto alloc = [&](size_t bytes) -> void* {
    void* p = wsp + off; off += (bytes + 255) & ~(size_t)255; return p;
  };
  __hip_bfloat16* WT  = (__hip_bfloat16*)alloc((size_t)12*512*512*2);
  float* x            = (float*)alloc((size_t)T1N*DMODEL*4);
  __hip_bfloat16* xb  = (__hip_bfloat16*)alloc((size_t)T1N*DMODEL*2);
  float* qf           = (float*)alloc((size_t)T1N*DMODEL*4);
  float* kf           = (float*)alloc((size_t)T1N*DMODEL*4);
  float* vf           = (float*)alloc((size_t)T1N*DMODEL*4);
  float* y            = (float*)alloc((size_t)T1N*DMODEL*4);
  __hip_bfloat16* ab  = (__hip_bfloat16*)alloc((size_t)T1N*DMODEL*2);
  __hip_bfloat16* f1b = (__hip_bfloat16*)alloc((size_t)T1N*DMODEL*2);
  int* ss             = (int*)alloc((size_t)T_TOK*4);

  wt_kernel<<<dim3(16,16,12), 256, 0, stream>>>(Wq, Wk, Wv, Wo, W1, W2, WT);
  embed_kernel<<<dim3(T1N), 256, 0, stream>>>(aseq, bid, W_type, b_type, W_arg, b_arg, sosv, x, xb, ss);

  const size_t WSZ = (size_t)512*512;
  const dim3 ggrid(65, 8);
  for (int l = 0; l < 2; l++) {
    const __hip_bfloat16* Bq  = WT + (size_t)(0*2+l)*WSZ;
    const __hip_bfloat16* Bk  = WT + (size_t)(1*2+l)*WSZ;
    const __hip_bfloat16* Bv  = WT + (size_t)(2*2+l)*WSZ;
    const __hip_bfloat16* Bo  = WT + (size_t)(3*2+l)*WSZ;
    const __hip_bfloat16* Bf1 = WT + (size_t)(4*2+l)*WSZ;
    const __hip_bfloat16* Bf2 = WT + (size_t)(5*2+l)*WSZ;

    gemm_qkv<<<dim3(65,8,3), 256, 0, stream>>>(xb, Bq, Bk, Bv,
        bq + l*512, bk + l*512, bv + l*512, qf, kf, vf, T1N);
    attn_kernel<<<dim3(65,8), 256, 0, stream>>>(qf, kf, vf, ss, ab);
    gemm_one<0,true,false><<<ggrid, 256, 0, stream>>>(ab, Bo, bo + l*512, y, nullptr, T1N);
    ln_kernel<<<dim3(T1N), 256, 0, stream>>>(x, y, ln1g + l*512, ln1b + l*512, x, xb);
    gemm_one<1,false,true><<<ggrid, 256, 0, stream>>>(xb, Bf1, b1 + l*512, nullptr, f1b, T1N);
    gemm_one<0,true,false><<<ggrid, 256, 0, stream>>>(f1b, Bf2, b2 + l*512, y, nullptr, T1N);
    float* xout = (l == 1) ? (float*)d_out : x;
    ln_kernel<<<dim3(T1N), 256, 0, stream>>>(x, y, ln2g + l*512, ln2b + l*512, xout, xb);
  }
}

// Round 3
// 217.818 us; speedup vs baseline: 1.9798x; 1.9798x over previous
//
#include <hip/hip_runtime.h>
#include <hip/hip_bf16.h>
#include <stdint.h>

#define T_TOK 4096
#define T1N   4097
#define DMODEL 512
#define VTS   4160   // padded column count of transposed V (65*64)

typedef __attribute__((ext_vector_type(8))) short bf16x8;
typedef __attribute__((ext_vector_type(4))) float f32x4;

static __device__ __forceinline__ unsigned short f2bf(float f) {
  __hip_bfloat16 h = __float2bfloat16(f);
  return *reinterpret_cast<unsigned short*>(&h);
}

// ---------------- weight transpose + bf16 cast: out[m][n][k] = W[m.layer][k][n] ----------------
__global__ __launch_bounds__(256) void wt_kernel(
    const float* __restrict__ Wq, const float* __restrict__ Wk,
    const float* __restrict__ Wv, const float* __restrict__ Wo,
    const float* __restrict__ W1, const float* __restrict__ W2,
    __hip_bfloat16* __restrict__ out) {
  int m = blockIdx.z;          // 0..11 : kind*2 + layer
  int kind = m >> 1, layer = m & 1;
  const float* src = kind==0?Wq: kind==1?Wk: kind==2?Wv: kind==3?Wo: kind==4?W1:W2;
  src += (size_t)layer*DMODEL*DMODEL;
  __hip_bfloat16* dst = out + (size_t)m*DMODEL*DMODEL;
  __shared__ float tile[32][33];
  int bn = blockIdx.x*32;   // n block
  int bk = blockIdx.y*32;   // k block
  int tx = threadIdx.x & 31, ty = threadIdx.x >> 5;
  for (int r = ty; r < 32; r += 8)
    tile[r][tx] = src[(size_t)(bk + r)*DMODEL + bn + tx];   // tile[kk][nn]
  __syncthreads();
  for (int r = ty; r < 32; r += 8)
    dst[(size_t)(bn + r)*DMODEL + bk + tx] = __float2bfloat16(tile[tx][r]); // dst[n][k]=src[k][n]
}

// ---------------- embedding + sinusoidal PE + seg_start ----------------
__global__ __launch_bounds__(256) void embed_kernel(
    const int* __restrict__ aseq, const int* __restrict__ bid,
    const float* __restrict__ Wt, const float* __restrict__ bt,
    const float* __restrict__ Wa, const float* __restrict__ ba,
    const float* __restrict__ sosv,
    float* __restrict__ x, __hip_bfloat16* __restrict__ xb,
    int* __restrict__ ss) {
  int i = blockIdx.x;
  int tid = threadIdx.x;
  int d0 = tid * 2;
  float o0, o1;
  if (i == 0) {
    o0 = sosv[d0]; o1 = sosv[d0+1];
  } else {
    int t = i - 1;
    int a0 = aseq[2*t], a1 = aseq[2*t+1];
    int key = bid[t];
    int lo = 0, hi = t;
    while (lo < hi) { int mid = (lo+hi) >> 1; if (bid[mid] < key) lo = mid + 1; else hi = mid; }
    if (tid == 0) ss[t] = lo;
    float pos = (float)(t - lo);
    float dv = __expf(-9.210340371976184f * (float)d0 * (1.0f/(float)DMODEL));
    float ang = pos * dv;
    float sn = sinf(ang), cs = cosf(ang);
    o0 = Wt[(size_t)a0*DMODEL + d0]   + bt[d0]   + Wa[(size_t)(a1+1)*DMODEL + d0]   + ba[d0]   + sn;
    o1 = Wt[(size_t)a0*DMODEL + d0+1] + bt[d0+1] + Wa[(size_t)(a1+1)*DMODEL + d0+1] + ba[d0+1] + cs;
  }
  size_t base = (size_t)i*DMODEL + d0;
  x[base] = o0; x[base+1] = o1;
  xb[base] = __float2bfloat16(o0); xb[base+1] = __float2bfloat16(o1);
}

// ---------------- bf16 MFMA GEMM: C[M,512] = A[M,512] @ B + bias ; B given as Bt[n][k] ----------------
template<int ACT, bool WF32, bool WB16>
__device__ __forceinline__ void gemm_body(
    const __hip_bfloat16* __restrict__ A, const __hip_bfloat16* __restrict__ Bt,
    const float* __restrict__ bias, float* __restrict__ Cf,
    __hip_bfloat16* __restrict__ Cb, int M) {
  constexpr int K = 512, N = 512;
  __shared__ __align__(16) __hip_bfloat16 As[64][72];
  __shared__ __align__(16) __hip_bfloat16 Bs[64][72];
  const int tid = threadIdx.x;
  const int m0 = blockIdx.x * 64;
  const int n0 = blockIdx.y * 64;
  const int lane = tid & 63, wave = tid >> 6;
  const int wm = wave >> 1, wn = wave & 1;
  f32x4 acc[2][2] = {};
  const int r0 = tid >> 3;          // 0..31
  const int koff = (tid & 7) * 8;   // 0..56
  const uint4 zero4 = {0,0,0,0};
  for (int k0 = 0; k0 < K; k0 += 64) {
    __syncthreads();
    #pragma unroll
    for (int rr = 0; rr < 2; rr++) {
      int row = r0 + rr*32;
      int grow = m0 + row;
      uint4 av = (grow < M) ? *(const uint4*)(A + (size_t)grow*K + k0 + koff) : zero4;
      *(uint4*)&As[row][koff] = av;
      uint4 bv = *(const uint4*)(Bt + (size_t)(n0+row)*K + k0 + koff);
      *(uint4*)&Bs[row][koff] = bv;
    }
    __syncthreads();
    #pragma unroll
    for (int kc = 0; kc < 64; kc += 32) {
      bf16x8 af[2], bf[2];
      #pragma unroll
      for (int i2 = 0; i2 < 2; i2++) {
        af[i2] = *(const bf16x8*)&As[wm*32 + i2*16 + (lane&15)][kc + (lane>>4)*8];
        bf[i2] = *(const bf16x8*)&Bs[wn*32 + i2*16 + (lane&15)][kc + (lane>>4)*8];
      }
      #pragma unroll
      for (int mi = 0; mi < 2; mi++)
        #pragma unroll
        for (int ni = 0; ni < 2; ni++)
          acc[mi][ni] = __builtin_amdgcn_mfma_f32_16x16x32_bf16(af[mi], bf[ni], acc[mi][ni], 0, 0, 0);
    }
  }
  #pragma unroll
  for (int mi = 0; mi < 2; mi++) {
    int rbase = m0 + wm*32 + mi*16 + ((lane>>4)<<2);
    #pragma unroll
    for (int ni = 0; ni < 2; ni++) {
      int col = n0 + wn*32 + ni*16 + (lane&15);
      float bb = bias[col];
      #pragma unroll
      for (int r = 0; r < 4; r++) {
        int row = rbase + r;
        if (row < M) {
          float val = acc[mi][ni][r] + bb;
          if (ACT == 1) val = fmaxf(val, 0.0f);
          if (WF32) Cf[(size_t)row*N + col] = val;
          if (WB16) Cb[(size_t)row*N + col] = __float2bfloat16(val);
        }
      }
    }
  }
}

template<int ACT, bool WF32, bool WB16>
__global__ __launch_bounds__(256) void gemm_one(
    const __hip_bfloat16* __restrict__ A, const __hip_bfloat16* __restrict__ Bt,
    const float* __restrict__ bias, float* __restrict__ Cf,
    __hip_bfloat16* __restrict__ Cb, int M) {
  gemm_body<ACT,WF32,WB16>(A, Bt, bias, Cf, Cb, M);
}

__global__ __launch_bounds__(256) void gemm_qkv(
    const __hip_bfloat16* __restrict__ A,
    const __hip_bfloat16* __restrict__ B0, const __hip_bfloat16* __restrict__ B1,
    const __hip_bfloat16* __restrict__ B2,
    const float* __restrict__ bias0, const float* __restrict__ bias1, const float* __restrict__ bias2,
    __hip_bfloat16* __restrict__ C0, __hip_bfloat16* __restrict__ C1, __hip_bfloat16* __restrict__ C2,
    int M) {
  int z = blockIdx.z;
  const __hip_bfloat16* Bt = (z==0) ? B0 : (z==1) ? B1 : B2;
  const float* bias = (z==0) ? bias0 : (z==1) ? bias1 : bias2;
  __hip_bfloat16* Cb = (z==0) ? C0 : (z==1) ? C1 : C2;
  gemm_body<0,false,true>(A, Bt, bias, nullptr, Cb, M);
}

// ---------------- V transpose: vt[d][t] = v[t][d]  (bf16, zero-padded cols to VTS) ----------------
__global__ __launch_bounds__(256) void vtrans_kernel(
    const short* __restrict__ vb, short* __restrict__ vt) {
  __shared__ short tile[64][72];
  int t0 = blockIdx.x*64, d0 = blockIdx.y*64;
  int c8 = threadIdx.x & 7, rr = threadIdx.x >> 3;   // rr 0..31
  #pragma unroll
  for (int i = 0; i < 2; i++) {
    int trow = rr + 32*i;
    bf16x8 val;
    if (t0 + trow < T1N) val = *(const bf16x8*)(vb + (size_t)(t0+trow)*DMODEL + d0 + c8*8);
    else val = (bf16x8){0,0,0,0,0,0,0,0};
    #pragma unroll
    for (int e = 0; e < 8; e++) tile[c8*8+e][trow] = val[e];
  }
  __syncthreads();
  #pragma unroll
  for (int i = 0; i < 2; i++) {
    int drow = rr + 32*i;
    bf16x8 oval = *(const bf16x8*)&tile[drow][c8*8];
    *(bf16x8*)(vt + (size_t)(d0+drow)*VTS + t0 + c8*8) = oval;
  }
}

// ---------------- MFMA block-sparse flash attention ----------------
// 1 wave = 16 queries x 1 head. Swapped QK^T (S^T = mfma(K,Q)); P redistributed to the
// PV A-fragment layout via packed __shfl (no LDS, no barriers); V from pre-transposed vt[d][t].
__global__ __launch_bounds__(64) void attn_kernel(
    const __hip_bfloat16* __restrict__ q,   // [T1N][512] bf16
    const __hip_bfloat16* __restrict__ k,   // [T1N][512] bf16
    const __hip_bfloat16* __restrict__ vt,  // [512][VTS] bf16
    const int* __restrict__ ss,
    __hip_bfloat16* __restrict__ out) {
  const int h  = blockIdx.y;
  const int q0 = blockIdx.x * 16;
  const int lane = threadIdx.x;
  const int g  = lane >> 4;      // 0..3
  const int qi = lane & 15;      // 0..15
  const int qrow = q0 + qi;      // softmax-role query of this lane

  // Q fragment (B operand): lane holds Q[q0+qi][h*64 + g*8 + e], plus +32 slice
  int qld = (qrow < T1N) ? qrow : (T1N-1);
  const __hip_bfloat16* qp = q + (size_t)qld*DMODEL + h*64 + g*8;
  bf16x8 qlo = *(const bf16x8*)qp;
  bf16x8 qhi = *(const bf16x8*)(qp + 32);

  int jl;                       // first allowed non-SOS key for this query
  if (qrow >= T1N)      jl = 0x7fffffff;
  else if (qrow == 0)   jl = 1;
  else                  jl = ss[qrow-1] + 1;

  // ---- SOS init: every query attends key 0; m := s(sos), weight 1 ----
  const __hip_bfloat16* k0p = k + h*64 + g*8;
  float part = 0.0f;
  #pragma unroll
  for (int e = 0; e < 8; e++) {
    part += __bfloat162float(((const __hip_bfloat16*)&qlo)[e]) * __bfloat162float(k0p[e]);
    part += __bfloat162float(((const __hip_bfloat16*)&qhi)[e]) * __bfloat162float(k0p[e+32]);
  }
  part += __shfl_xor(part, 16);
  part += __shfl_xor(part, 32);
  float m = part * 0.125f;
  float lsum = 1.0f;             // full per-query denominator (kept identical across g-lanes)
  f32x4 o[4];
  #pragma unroll
  for (int d = 0; d < 4; d++) {
    float v0 = __bfloat162float(vt[(size_t)(h*64 + d*16 + qi)*VTS]);
    o[d] = (f32x4){v0, v0, v0, v0};
  }

  const int mjl = (q0 == 0) ? 1 : (ss[q0-1] + 1);   // min jl over wave (ss monotone)
  const int kb_lo = mjl & ~31;
  const int jmax = (q0 + 15 < T1N - 1) ? (q0 + 15) : (T1N - 1);

  const int src0 = ((g & 1) << 5) + qi;   // P-redistribution source lanes
  const bool hiHalf = (g >= 2);

  for (int kbb = kb_lo; kbb <= jmax; kbb += 32) {
    // K fragments (A operand): tile0 keys kbb..kbb+15, tile1 keys kbb+16..kbb+31
    int kr0 = kbb + qi;       if (kr0 > T1N-1) kr0 = T1N-1;
    int kr1 = kbb + 16 + qi;  if (kr1 > T1N-1) kr1 = T1N-1;
    const __hip_bfloat16* kp0 = k + (size_t)kr0*DMODEL + h*64 + g*8;
    const __hip_bfloat16* kp1 = k + (size_t)kr1*DMODEL + h*64 + g*8;
    bf16x8 ka_lo = *(const bf16x8*)kp0, ka_hi = *(const bf16x8*)(kp0 + 32);
    bf16x8 kb_l  = *(const bf16x8*)kp1, kb_h  = *(const bf16x8*)(kp1 + 32);
    // V fragments (B operand for PV, K=32): lane holds Vt[h*64+d*16+qi][kbb + g*8 + e]
    bf16x8 vf[4];
    #pragma unroll
    for (int d = 0; d < 4; d++)
      vf[d] = *(const bf16x8*)(vt + (size_t)(h*64 + d*16 + qi)*VTS + kbb + g*8);

    // S^T tiles: D[key][query]; lane (g,qi) reg r -> key kbb(+16) + 4g+r, query q0+qi
    f32x4 sA = {0,0,0,0}, sB = {0,0,0,0};
    sA = __builtin_amdgcn_mfma_f32_16x16x32_bf16(ka_lo, qlo, sA, 0, 0, 0);
    sA = __builtin_amdgcn_mfma_f32_16x16x32_bf16(ka_hi, qhi, sA, 0, 0, 0);
    sB = __builtin_amdgcn_mfma_f32_16x16x32_bf16(kb_l,  qlo, sB, 0, 0, 0);
    sB = __builtin_amdgcn_mfma_f32_16x16x32_bf16(kb_h,  qhi, sB, 0, 0, 0);

    // mask + scale
    float s[8];
    const int kA = kbb + 4*g, kB = kA + 16;
    #pragma unroll
    for (int r = 0; r < 4; r++) {
      s[r]   = (kA + r >= jl && kA + r <= qrow) ? sA[r]*0.125f : -1e30f;
      s[4+r] = (kB + r >= jl && kB + r <= qrow) ? sB[r]*0.125f : -1e30f;
    }
    float mx = s[0];
    #pragma unroll
    for (int i = 1; i < 8; i++) mx = fmaxf(mx, s[i]);
    mx = fmaxf(mx, __shfl_xor(mx, 16));
    mx = fmaxf(mx, __shfl_xor(mx, 32));
    float mnew = fmaxf(m, mx);
    float corr = __expf(m - mnew);
    m = mnew;
    float p[8], psum = 0.0f;
    #pragma unroll
    for (int i = 0; i < 8; i++) { p[i] = __expf(s[i] - mnew); psum += p[i]; }
    psum += __shfl_xor(psum, 16);          // full per-query sum (FIX: was missing)
    psum += __shfl_xor(psum, 32);
    lsum = lsum*corr + psum;

    // ---- redistribute P to the PV A-fragment layout: pa[e] = bf16(P[qi][8g+e]) ----
    // pack (tileA p[r], tileB p[4+r]) into one u32, shuffle twice, select half by g>=2
    bf16x8 pa;
    #pragma unroll
    for (int r = 0; r < 4; r++) {
      unsigned w = (unsigned)f2bf(p[r]) | ((unsigned)f2bf(p[4+r]) << 16);
      unsigned v0 = (unsigned)__shfl((int)w, src0);
      unsigned v1 = (unsigned)__shfl((int)w, src0 + 16);
      pa[r]     = (short)(hiHalf ? (v0 >> 16) : (v0 & 0xffff));
      pa[4 + r] = (short)(hiHalf ? (v1 >> 16) : (v1 & 0xffff));
    }

    // rescale accumulator: acc row r of this lane is query 4g+r; corr uniform across g-groups
    float cq0 = __shfl(corr, 4*g + 0);
    float cq1 = __shfl(corr, 4*g + 1);
    float cq2 = __shfl(corr, 4*g + 2);
    float cq3 = __shfl(corr, 4*g + 3);
    f32x4 cqv = (f32x4){cq0, cq1, cq2, cq3};
    #pragma unroll
    for (int d = 0; d < 4; d++) o[d] *= cqv;

    #pragma unroll
    for (int d = 0; d < 4; d++)
      o[d] = __builtin_amdgcn_mfma_f32_16x16x32_bf16(pa, vf[d], o[d], 0, 0, 0);
  }

  // epilogue: lane holds O[q0+4g+r][h*64 + d*16 + qi]
  float inv = 1.0f / lsum;
  float li0 = __shfl(inv, 4*g + 0);
  float li1 = __shfl(inv, 4*g + 1);
  float li2 = __shfl(inv, 4*g + 2);
  float li3 = __shfl(inv, 4*g + 3);
  f32x4 liv = (f32x4){li0, li1, li2, li3};
  #pragma unroll
  for (int r = 0; r < 4; r++) {
    int row = q0 + 4*g + r;
    if (row < T1N) {
      __hip_bfloat16* op = out + (size_t)row*DMODEL + h*64 + qi;
      #pragma unroll
      for (int d = 0; d < 4; d++) op[d*16] = __float2bfloat16(o[d][r] * liv[r]);
    }
  }
}

// ---------------- residual + LayerNorm ----------------
__global__ __launch_bounds__(256) void ln_kernel(
    const float* __restrict__ xin, const float* __restrict__ yin,
    const float* __restrict__ g, const float* __restrict__ b,
    float* __restrict__ xout, __hip_bfloat16* __restrict__ xbout) {
  int row = blockIdx.x;
  int tid = threadIdx.x;
  const float* xp = xin + (size_t)row*DMODEL;
  const float* yp = yin + (size_t)row*DMODEL;
  float v0 = xp[tid] + yp[tid];
  float v1 = xp[tid+256] + yp[tid+256];
  float s = v0 + v1, sq = v0*v0 + v1*v1;
  #pragma unroll
  for (int off = 1; off < 64; off <<= 1) {
    s  += __shfl_xor(s, off);
    sq += __shfl_xor(sq, off);
  }
  __shared__ float ls[4], lq[4];
  int wave = tid >> 6;
  if ((tid & 63) == 0) { ls[wave] = s; lq[wave] = sq; }
  __syncthreads();
  s  = ls[0] + ls[1] + ls[2] + ls[3];
  sq = lq[0] + lq[1] + lq[2] + lq[3];
  float mean = s * (1.0f/512.0f);
  float var  = sq * (1.0f/512.0f) - mean*mean;
  float rstd = rsqrtf(var + 1e-5f);
  float o0 = (v0 - mean)*rstd*g[tid]     + b[tid];
  float o1 = (v1 - mean)*rstd*g[tid+256] + b[tid+256];
  size_t base = (size_t)row*DMODEL;
  xout[base + tid]       = o0;
  xout[base + tid + 256] = o1;
  xbout[base + tid]       = __float2bfloat16(o0);
  xbout[base + tid + 256] = __float2bfloat16(o1);
}

extern "C" void kernel_launch(void* const* d_in, const int* in_sizes, int n_in,
                              void* d_out, int out_size, void* d_ws, size_t ws_size,
                              hipStream_t stream) {
  const int*   aseq   = (const int*)d_in[0];
  const int*   bid    = (const int*)d_in[1];
  const float* W_type = (const float*)d_in[2];
  const float* b_type = (const float*)d_in[3];
  const float* W_arg  = (const float*)d_in[4];
  const float* b_arg  = (const float*)d_in[5];
  const float* sosv   = (const float*)d_in[6];
  const float* Wq = (const float*)d_in[7];
  const float* bq = (const float*)d_in[8];
  const float* Wk = (const float*)d_in[9];
  const float* bk = (const float*)d_in[10];
  const float* Wv = (const float*)d_in[11];
  const float* bv = (const float*)d_in[12];
  const float* Wo = (const float*)d_in[13];
  const float* bo = (const float*)d_in[14];
  const float* ln1g = (const float*)d_in[15];
  const float* ln1b = (const float*)d_in[16];
  const float* W1 = (const float*)d_in[17];
  const float* b1 = (const float*)d_in[18];
  const float* W2 = (const float*)d_in[19];
  const float* b2 = (const float*)d_in[20];
  const float* ln2g = (const float*)d_in[21];
  const float* ln2b = (const float*)d_in[22];

  char* wsp = (char*)d_ws;
  size_t off = 0;
  auto alloc = [&](size_t bytes) -> void* {
    void* p = wsp + off; off += (bytes + 255) & ~(size_t)255; return p;
  };
  __hip_bfloat16* WT  = (__hip_bfloat16*)alloc((size_t)12*512*512*2);
  float* x            = (float*)alloc((size_t)T1N*DMODEL*4);
  __hip_bfloat16* xb  = (__hip_bfloat16*)alloc((size_t)T1N*DMODEL*2);
  __hip_bfloat16* qb  = (__hip_bfloat16*)alloc((size_t)T1N*DMODEL*2);
  __hip_bfloat16* kbf = (__hip_bfloat16*)alloc((size_t)T1N*DMODEL*2);
  __hip_bfloat16* vb  = (__hip_bfloat16*)alloc((size_t)T1N*DMODEL*2);
  __hip_bfloat16* vtb = (__hip_bfloat16*)alloc((size_t)512*VTS*2);
  float* y            = (float*)alloc((size_t)T1N*DMODEL*4);
  __hip_bfloat16* ab  = (__hip_bfloat16*)alloc((size_t)T1N*DMODEL*2);
  __hip_bfloat16* f1b = (__hip_bfloat16*)alloc((size_t)T1N*DMODEL*2);
  int* ss             = (int*)alloc((size_t)T_TOK*4);

  wt_kernel<<<dim3(16,16,12), 256, 0, stream>>>(Wq, Wk, Wv, Wo, W1, W2, WT);
  embed_kernel<<<dim3(T1N), 256, 0, stream>>>(aseq, bid, W_type, b_type, W_arg, b_arg, sosv, x, xb, ss);

  const size_t WSZ = (size_t)512*512;
  const dim3 ggrid(65, 8);
  for (int l = 0; l < 2; l++) {
    const __hip_bfloat16* Bq  = WT + (size_t)(0*2+l)*WSZ;
    const __hip_bfloat16* Bk  = WT + (size_t)(1*2+l)*WSZ;
    const __hip_bfloat16* Bv  = WT + (size_t)(2*2+l)*WSZ;
    const __hip_bfloat16* Bo  = WT + (size_t)(3*2+l)*WSZ;
    const __hip_bfloat16* Bf1 = WT + (size_t)(4*2+l)*WSZ;
    const __hip_bfloat16* Bf2 = WT + (size_t)(5*2+l)*WSZ;

    gemm_qkv<<<dim3(65,8,3), 256, 0, stream>>>(xb, Bq, Bk, Bv,
        bq + l*512, bk + l*512, bv + l*512, qb, kbf, vb, T1N);
    vtrans_kernel<<<dim3(65,8), 256, 0, stream>>>((const short*)vb, (short*)vtb);
    attn_kernel<<<dim3(257,8), 64, 0, stream>>>(qb, kbf, vtb, ss, ab);
    gemm_one<0,true,false><<<ggrid, 256, 0, stream>>>(ab, Bo, bo + l*512, y, nullptr, T1N);
    ln_kernel<<<dim3(T1N), 256, 0, stream>>>(x, y, ln1g + l*512, ln1b + l*512, x, xb);
    gemm_one<1,false,true><<<ggrid, 256, 0, stream>>>(xb, Bf1, b1 + l*512, nullptr, f1b, T1N);
    gemm_one<0,true,false><<<ggrid, 256, 0, stream>>>(f1b, Bf2, b2 + l*512, y, nullptr, T1N);
    float* xout = (l == 1) ? (float*)d_out : x;
    ln_kernel<<<dim3(T1N), 256, 0, stream>>>(x, y, ln2g + l*512, ln2b + l*512, xout, xb);
  }
}